// Round 1
// baseline (1503.863 us; speedup 1.0000x reference)
//
#include <hip/hip_runtime.h>

// ---------------------------------------------------------------------------
// MultiHeadAttention: B=4, NQ=NK=2048, H=16, DK=DV=64, DIM=1024 (fp32 in/out)
// Outputs: o [4,2048,1024] then weights [4,16,2048,2048], concatenated fp32.
//
// Pipeline (all bf16 MFMA 16x16x32, fp32 accum):
//   cast_w x4   : W* fp32 -> bf16 (ws)
//   gemm_proj   : q/k/v projections; A fp32 converted during staging.
//                 q,k stored head-major [b,h,n,64]; v stored transposed [b,h,64,n]
//   attn_fused  : per (b,h,64-row q-block): pass1 = row sum of exp(s*scale)
//                 (no max-subtract: logits ~N(0,0.41), overflow impossible);
//                 pass2 = recompute S, write normalized weights fp32 to d_out,
//                 P -> LDS (C-layout -> A-layout) -> PV accumulate.
//   gemm_out    : o = Oattn @ Wo^T -> fp32 d_out
//
// ws layout (72 MiB): wq16@0 wk16@2M wv16@4M wo16@6M qh@8M kh@24M vT@40M oat@56M
// ---------------------------------------------------------------------------

typedef __attribute__((ext_vector_type(8))) short s16x8;
typedef __attribute__((ext_vector_type(4))) float f32x4;
typedef __attribute__((ext_vector_type(4))) unsigned int u32x4;
typedef __attribute__((ext_vector_type(4))) unsigned short u16x4;

#define MFMA16(a, b, c) __builtin_amdgcn_mfma_f32_16x16x32_bf16((a), (b), (c), 0, 0, 0)

__device__ __forceinline__ unsigned short f2bf(float f) {
    unsigned int u = __builtin_bit_cast(unsigned int, f);
    u = u + 0x7FFFu + ((u >> 16) & 1u);   // RTNE (no NaNs in this problem)
    return (unsigned short)(u >> 16);
}

// ---------------- cast fp32 -> bf16, 1M elements (weight matrices) ----------
__global__ __launch_bounds__(256) void cast_w(const float* __restrict__ in,
                                              unsigned short* __restrict__ out) {
    int i = blockIdx.x * 256 + threadIdx.x;      // 1024 blocks * 256 thr * 4 elems
    f32x4 v = *(const f32x4*)(in + (size_t)i * 4);
    u16x4 o;
    o.x = f2bf(v.x); o.y = f2bf(v.y); o.z = f2bf(v.z); o.w = f2bf(v.w);
    *(u16x4*)(out + (size_t)i * 4) = o;
}

// ---------------- projection GEMM: [8192x1024] @ [1024x1024]^T --------------
// z=0: query@Wq -> qh head-major; z=1: key@Wk -> kh head-major;
// z=2: value@Wv -> vT transposed.
__global__ __launch_bounds__(256) void gemm_proj(
    const float* __restrict__ query, const float* __restrict__ key,
    const float* __restrict__ value,
    const unsigned short* __restrict__ wq, const unsigned short* __restrict__ wk,
    const unsigned short* __restrict__ wv,
    unsigned short* __restrict__ qh, unsigned short* __restrict__ kh,
    unsigned short* __restrict__ vT) {
    __shared__ __attribute__((aligned(16))) unsigned short sA[128 * 32];
    __shared__ __attribute__((aligned(16))) unsigned short sB[128 * 32];

    const int z = blockIdx.z;
    const float* A = (z == 0) ? query : (z == 1) ? key : value;
    const unsigned short* W = (z == 0) ? wq : (z == 1) ? wk : wv;

    const int tid = threadIdx.x;
    const int m0 = blockIdx.y * 128;
    const int n0 = blockIdx.x * 128;
    const int lane = tid & 63;
    const int w = tid >> 6;
    const int wm = (w >> 1) * 64, wn = (w & 1) * 64;
    const int q = lane >> 4, c = lane & 15;

    const f32x4 fzero = {0.f, 0.f, 0.f, 0.f};
    f32x4 acc[4][4];
#pragma unroll
    for (int i = 0; i < 4; i++)
#pragma unroll
        for (int j = 0; j < 4; j++) acc[i][j] = fzero;

    for (int k0 = 0; k0 < 1024; k0 += 32) {
        // stage A (fp32 -> bf16): 128x32, 4 float4 per thread
#pragma unroll
        for (int j = 0; j < 4; j++) {
            int chunk = j * 256 + tid;                 // 0..1023, 4 floats each
            int r = chunk >> 3, c4 = (chunk & 7) << 2;
            f32x4 v = *(const f32x4*)(A + (size_t)(m0 + r) * 1024 + k0 + c4);
            u16x4 o;
            o.x = f2bf(v.x); o.y = f2bf(v.y); o.z = f2bf(v.z); o.w = f2bf(v.w);
            *(u16x4*)(&sA[r * 32 + c4]) = o;
        }
        // stage B (bf16): 128x32, 2 x 8 elems per thread
#pragma unroll
        for (int j = 0; j < 2; j++) {
            int chunk = j * 256 + tid;                 // 0..511, 8 elems each
            int r = chunk >> 2, c8 = (chunk & 3) << 3;
            *(u32x4*)(&sB[r * 32 + c8]) =
                *(const u32x4*)(W + (size_t)(n0 + r) * 1024 + k0 + c8);
        }
        __syncthreads();
        s16x8 fa[4], fb[4];
#pragma unroll
        for (int mt = 0; mt < 4; mt++)
            fa[mt] = *(const s16x8*)(&sA[(wm + mt * 16 + c) * 32 + q * 8]);
#pragma unroll
        for (int nt = 0; nt < 4; nt++)
            fb[nt] = *(const s16x8*)(&sB[(wn + nt * 16 + c) * 32 + q * 8]);
#pragma unroll
        for (int mt = 0; mt < 4; mt++)
#pragma unroll
            for (int nt = 0; nt < 4; nt++)
                acc[mt][nt] = MFMA16(fa[mt], fb[nt], acc[mt][nt]);
        __syncthreads();
    }

    unsigned short* outp = (z == 0) ? qh : (z == 1) ? kh : vT;
    const bool trans = (z == 2);
#pragma unroll
    for (int mt = 0; mt < 4; mt++) {
#pragma unroll
        for (int i = 0; i < 4; i++) {
            int m = m0 + wm + mt * 16 + q * 4 + i;     // global row
            int bidx = m >> 11, nseq = m & 2047;
#pragma unroll
            for (int nt = 0; nt < 4; nt++) {
                int jcol = n0 + wn + nt * 16 + c;
                int h = jcol >> 6, d = jcol & 63;
                size_t dst = trans
                    ? ((size_t)(bidx * 16 + h) * 64 + d) * 2048 + nseq
                    : ((size_t)(bidx * 16 + h) * 2048 + nseq) * 64 + d;
                outp[dst] = f2bf(acc[mt][nt][i]);
            }
        }
    }
}

// ---------------- fused attention ------------------------------------------
// block = (qblock 0..31, h 0..15, b 0..3), 256 threads = 4 waves,
// wave w owns q-rows [w*16, w*16+16) of the 64-row block.
__global__ __launch_bounds__(256) void attn_fused(
    const unsigned short* __restrict__ qh, const unsigned short* __restrict__ kh,
    const unsigned short* __restrict__ vT,
    float* __restrict__ Wout, unsigned short* __restrict__ Oattn) {
    __shared__ __attribute__((aligned(16))) unsigned short sQ[64 * 64];    // 8 KB
    __shared__ __attribute__((aligned(16))) unsigned short sK[128 * 64];   // 16 KB
    __shared__ __attribute__((aligned(16))) unsigned short sV[64 * 128];   // 16 KB
    __shared__ __attribute__((aligned(16))) unsigned short sP[4 * 16 * 128]; // 16 KB

    const int qb = blockIdx.x, h = blockIdx.y, b = blockIdx.z;
    const int tid = threadIdx.x, lane = tid & 63, w = tid >> 6;
    const int q = lane >> 4, c = lane & 15;

    const unsigned short* qptr = qh + ((size_t)(b * 16 + h) * 2048 + qb * 64) * 64;
    const unsigned short* kptr = kh + (size_t)(b * 16 + h) * 2048 * 64;
    const unsigned short* vptr = vT + (size_t)(b * 16 + h) * 64 * 2048;
    float* wptr = Wout + ((size_t)(b * 16 + h) * 2048 + (size_t)qb * 64) * 2048;

    // load Q block [64 x 64]
#pragma unroll
    for (int j = 0; j < 2; j++) {
        int chunk = j * 256 + tid;                     // 0..511, 8 elems each
        ((u32x4*)sQ)[chunk] = ((const u32x4*)qptr)[chunk];
    }

    const float scale = 0.125f;
    const f32x4 fzero = {0.f, 0.f, 0.f, 0.f};
    float rsum[4] = {0.f, 0.f, 0.f, 0.f};

    // ---- pass 1: row sums of exp(s*scale) ----
    for (int kt = 0; kt < 16; kt++) {
#pragma unroll
        for (int j = 0; j < 4; j++) {
            int chunk = j * 256 + tid;                 // 0..1023, 8 elems each
            ((u32x4*)sK)[chunk] =
                *(const u32x4*)(kptr + (size_t)kt * 8192 + (size_t)chunk * 8);
        }
        __syncthreads();
        f32x4 acc[8];
#pragma unroll
        for (int nt = 0; nt < 8; nt++) acc[nt] = fzero;
#pragma unroll
        for (int s = 0; s < 2; s++) {
            s16x8 fa = *(const s16x8*)(&sQ[(w * 16 + c) * 64 + s * 32 + q * 8]);
#pragma unroll
            for (int nt = 0; nt < 8; nt++) {
                s16x8 fb = *(const s16x8*)(&sK[(nt * 16 + c) * 64 + s * 32 + q * 8]);
                acc[nt] = MFMA16(fa, fb, acc[nt]);
            }
        }
#pragma unroll
        for (int nt = 0; nt < 8; nt++)
#pragma unroll
            for (int i = 0; i < 4; i++)
                rsum[i] += __expf(acc[nt][i] * scale);
        __syncthreads();
    }
#pragma unroll
    for (int i = 0; i < 4; i++) {
        rsum[i] += __shfl_xor(rsum[i], 1);
        rsum[i] += __shfl_xor(rsum[i], 2);
        rsum[i] += __shfl_xor(rsum[i], 4);
        rsum[i] += __shfl_xor(rsum[i], 8);
    }
    float rinv[4];
#pragma unroll
    for (int i = 0; i < 4; i++) rinv[i] = 1.0f / rsum[i];

    // ---- pass 2: recompute S, emit weights, accumulate PV ----
    f32x4 oacc[4];
#pragma unroll
    for (int i = 0; i < 4; i++) oacc[i] = fzero;

    for (int kt = 0; kt < 16; kt++) {
#pragma unroll
        for (int j = 0; j < 4; j++) {
            int chunk = j * 256 + tid;
            ((u32x4*)sK)[chunk] =
                *(const u32x4*)(kptr + (size_t)kt * 8192 + (size_t)chunk * 8);
        }
#pragma unroll
        for (int j = 0; j < 4; j++) {
            int chunk = j * 256 + tid;                 // vT tile [64 dv x 128 kn]
            int r = chunk >> 4, c8 = (chunk & 15) << 3;
            ((u32x4*)sV)[chunk] =
                *(const u32x4*)(vptr + (size_t)r * 2048 + kt * 128 + c8);
        }
        __syncthreads();
        f32x4 acc[8];
#pragma unroll
        for (int nt = 0; nt < 8; nt++) acc[nt] = fzero;
#pragma unroll
        for (int s = 0; s < 2; s++) {
            s16x8 fa = *(const s16x8*)(&sQ[(w * 16 + c) * 64 + s * 32 + q * 8]);
#pragma unroll
            for (int nt = 0; nt < 8; nt++) {
                s16x8 fb = *(const s16x8*)(&sK[(nt * 16 + c) * 64 + s * 32 + q * 8]);
                acc[nt] = MFMA16(fa, fb, acc[nt]);
            }
        }
        // normalize, write weights (fp32, streaming) + stage P to LDS (bf16)
#pragma unroll
        for (int nt = 0; nt < 8; nt++) {
#pragma unroll
            for (int i = 0; i < 4; i++) {
                float p = __expf(acc[nt][i] * scale) * rinv[i];
                int row = w * 16 + q * 4 + i;
                int col = kt * 128 + nt * 16 + c;
                __builtin_nontemporal_store(p, wptr + (size_t)row * 2048 + col);
                sP[w * 2048 + (q * 4 + i) * 128 + nt * 16 + c] = f2bf(p);
            }
        }
        __syncthreads();
        // PV: O[16x64] += P[16x128] @ V[128x64]  (B operand = vT tile)
#pragma unroll
        for (int s2 = 0; s2 < 4; s2++) {
            s16x8 fa = *(const s16x8*)(&sP[w * 2048 + c * 128 + s2 * 32 + q * 8]);
#pragma unroll
            for (int nt2 = 0; nt2 < 4; nt2++) {
                s16x8 fb = *(const s16x8*)(&sV[(nt2 * 16 + c) * 128 + s2 * 32 + q * 8]);
                oacc[nt2] = MFMA16(fa, fb, oacc[nt2]);
            }
        }
        __syncthreads();
    }

    // write Oattn bf16 [b, n, h*64+dv]
#pragma unroll
    for (int nt2 = 0; nt2 < 4; nt2++) {
#pragma unroll
        for (int i = 0; i < 4; i++) {
            int row = w * 16 + q * 4 + i;
            int dv = nt2 * 16 + c;
            Oattn[(size_t)(b * 2048 + qb * 64 + row) * 1024 + h * 64 + dv] =
                f2bf(oacc[nt2][i]);
        }
    }
}

// ---------------- output GEMM: o = Oattn[8192x1024] @ Wo^T -> fp32 ----------
__global__ __launch_bounds__(256) void gemm_out(
    const unsigned short* __restrict__ A, const unsigned short* __restrict__ W,
    float* __restrict__ out) {
    __shared__ __attribute__((aligned(16))) unsigned short sA[128 * 32];
    __shared__ __attribute__((aligned(16))) unsigned short sB[128 * 32];

    const int tid = threadIdx.x;
    const int m0 = blockIdx.y * 128;
    const int n0 = blockIdx.x * 128;
    const int lane = tid & 63;
    const int w = tid >> 6;
    const int wm = (w >> 1) * 64, wn = (w & 1) * 64;
    const int q = lane >> 4, c = lane & 15;

    const f32x4 fzero = {0.f, 0.f, 0.f, 0.f};
    f32x4 acc[4][4];
#pragma unroll
    for (int i = 0; i < 4; i++)
#pragma unroll
        for (int j = 0; j < 4; j++) acc[i][j] = fzero;

    for (int k0 = 0; k0 < 1024; k0 += 32) {
#pragma unroll
        for (int j = 0; j < 2; j++) {
            int chunk = j * 256 + tid;
            int r = chunk >> 2, c8 = (chunk & 3) << 3;
            *(u32x4*)(&sA[r * 32 + c8]) =
                *(const u32x4*)(A + (size_t)(m0 + r) * 1024 + k0 + c8);
        }
#pragma unroll
        for (int j = 0; j < 2; j++) {
            int chunk = j * 256 + tid;
            int r = chunk >> 2, c8 = (chunk & 3) << 3;
            *(u32x4*)(&sB[r * 32 + c8]) =
                *(const u32x4*)(W + (size_t)(n0 + r) * 1024 + k0 + c8);
        }
        __syncthreads();
        s16x8 fa[4], fb[4];
#pragma unroll
        for (int mt = 0; mt < 4; mt++)
            fa[mt] = *(const s16x8*)(&sA[(wm + mt * 16 + c) * 32 + q * 8]);
#pragma unroll
        for (int nt = 0; nt < 4; nt++)
            fb[nt] = *(const s16x8*)(&sB[(wn + nt * 16 + c) * 32 + q * 8]);
#pragma unroll
        for (int mt = 0; mt < 4; mt++)
#pragma unroll
            for (int nt = 0; nt < 4; nt++)
                acc[mt][nt] = MFMA16(fa[mt], fb[nt], acc[mt][nt]);
        __syncthreads();
    }

#pragma unroll
    for (int mt = 0; mt < 4; mt++) {
#pragma unroll
        for (int i = 0; i < 4; i++) {
            int m = m0 + wm + mt * 16 + q * 4 + i;
#pragma unroll
            for (int nt = 0; nt < 4; nt++) {
                int jcol = n0 + wn + nt * 16 + c;
                out[(size_t)m * 1024 + jcol] = acc[mt][nt][i];
            }
        }
    }
}

// ---------------------------------------------------------------------------
extern "C" void kernel_launch(void* const* d_in, const int* in_sizes, int n_in,
                              void* d_out, int out_size, void* d_ws, size_t ws_size,
                              hipStream_t stream) {
    (void)in_sizes; (void)n_in; (void)out_size; (void)ws_size;
    const float* query = (const float*)d_in[0];
    const float* key   = (const float*)d_in[1];
    const float* value = (const float*)d_in[2];
    const float* Wq    = (const float*)d_in[3];
    const float* Wk    = (const float*)d_in[4];
    const float* Wv    = (const float*)d_in[5];
    const float* Wo    = (const float*)d_in[6];
    float* out = (float*)d_out;

    char* ws = (char*)d_ws;
    unsigned short* wq16 = (unsigned short*)(ws);
    unsigned short* wk16 = (unsigned short*)(ws + (size_t)2  * 1024 * 1024);
    unsigned short* wv16 = (unsigned short*)(ws + (size_t)4  * 1024 * 1024);
    unsigned short* wo16 = (unsigned short*)(ws + (size_t)6  * 1024 * 1024);
    unsigned short* qh   = (unsigned short*)(ws + (size_t)8  * 1024 * 1024);
    unsigned short* kh   = (unsigned short*)(ws + (size_t)24 * 1024 * 1024);
    unsigned short* vT   = (unsigned short*)(ws + (size_t)40 * 1024 * 1024);
    unsigned short* oat  = (unsigned short*)(ws + (size_t)56 * 1024 * 1024);

    cast_w<<<1024, 256, 0, stream>>>(Wq, wq16);
    cast_w<<<1024, 256, 0, stream>>>(Wk, wk16);
    cast_w<<<1024, 256, 0, stream>>>(Wv, wv16);
    cast_w<<<1024, 256, 0, stream>>>(Wo, wo16);

    gemm_proj<<<dim3(8, 64, 3), 256, 0, stream>>>(query, key, value,
                                                  wq16, wk16, wv16, qh, kh, vT);

    attn_fused<<<dim3(32, 16, 4), 256, 0, stream>>>(qh, kh, vT,
                                                    out + 8388608, oat);

    gemm_out<<<dim3(8, 64), 256, 0, stream>>>(oat, wo16, out);
}